// Round 8
// baseline (8685.372 us; speedup 1.0000x reference)
//
#include <hip/hip_runtime.h>
#include <stdint.h>

typedef unsigned long long ull;

#define NEGINF_ORD 0x007FFFFFu

__device__ __forceinline__ unsigned ordf(float f) {
    unsigned u = __float_as_uint(f);
    return (u & 0x80000000u) ? ~u : (u | 0x80000000u);
}

__device__ __forceinline__ void gl16(const float* g, float* l) {
    __builtin_amdgcn_global_load_lds(
        (const __attribute__((address_space(1))) unsigned*)g,
        (__attribute__((address_space(3))) unsigned*)l, 16, 0, 0);
}

// ---------------- tiny prepass kernels ----------------
__global__ __launch_bounds__(256) void zero_fill(float* __restrict__ z) {
    z[threadIdx.x] = 0.f;   // 1KB zero page (256 floats)
}

// W [512][1024][3][3] -> Wt2[ot=4][k=9216][o=128]  (k = c*9 + kh*3 + kw)
__global__ __launch_bounds__(256) void reorder_w(const float* __restrict__ W, float* __restrict__ Wt2) {
    __shared__ float t[16][130];
    const int kb = blockIdx.x * 16;      // 576
    const int ot = blockIdx.y;           // 4
    const int tid = threadIdx.x;
#pragma unroll
    for (int r = 0; r < 8; ++r) {
        int e = tid + 256 * r;           // 0..2047
        int o_l = e >> 4, kk = e & 15;
        t[kk][o_l] = W[(size_t)(ot * 128 + o_l) * 9216 + kb + kk];
    }
    __syncthreads();
#pragma unroll
    for (int r = 0; r < 8; ++r) {
        int e = tid + 256 * r;
        int kk = e >> 7, o_l = e & 127;
        Wt2[((size_t)ot * 9216 + kb + kk) * 128 + o_l] = t[kk][o_l];
    }
}

// ---------------- conv 3x3 + bias + relu ----------------
// tile: O=128, H=2, W=64. 512 thr: tx=tid&15 (w=tx*4), hloc=(tid>>4)&1, ty=tid>>5 (o=ty*8)
// LDS: Wb[2][36k][128o] + Ib[2][4c][4r][64w]  (CK=4, double buffered) = 44KB
// amdgpu_waves_per_eu(2,2): pin pressure target at 2 waves/EU -> 256 VGPR budget.
// R3/R4 evidence: compiler's own heuristic targeted 4 waves/EU (VGPR=128) and
// spilled the 64-float accumulator to scratch (21 GB writes/dispatch).
__global__ __launch_bounds__(512)
__attribute__((amdgpu_waves_per_eu(2, 2)))
void conv3x3_kernel(
    const float* __restrict__ Wt2, const float* __restrict__ in,
    const float* __restrict__ zerop, const float* __restrict__ bc,
    float* __restrict__ xout)
{
    __shared__ __align__(16) float Wb[2][36 * 128];
    __shared__ __align__(16) float Ib[2][4 * 4 * 64];

    const int h0 = blockIdx.x * 2;
    const int ot = blockIdx.y;
    const int b  = blockIdx.z;
    const int tid = threadIdx.x;
    const int tx = tid & 15;
    const int hloc = (tid >> 4) & 1;
    const int ty = tid >> 5;        // 0..15
    const int wv = tid >> 6;        // wave 0..7
    const int ln = tid & 63;
    const int w0i = tx * 4;

    // staging lane mapping
    const int r_ln = ln >> 4;               // 0..3
    const int wc_ln = (ln & 15) * 4;
    const int hin = h0 - 1 + r_ln;
    const bool hok = (hin >= 0) && (hin < 64);
    const float* isrc = in + ((size_t)(b * 1024) * 64 + (hok ? hin : 0)) * 64 + wc_ln;
    const float* zsrc = zerop + ln * 4;
    const float* wsrc = Wt2 + (size_t)ot * 9216 * 128 + ln * 4;

    auto stage = [&](int cc, int buf) {
        // weights: 18 x 1KB wave-DMAs (2 k-rows each), split over 8 waves
        const float* wsB = wsrc + (size_t)cc * 36 * 128;
#pragma unroll
        for (int j = 0; j < 3; ++j) {
            int m = wv + 8 * j;
            if (m < 18)
                gl16(wsB + (size_t)m * 256, &Wb[buf][m * 256]);
        }
        // input: 4 channels, one 1KB wave-DMA each (4 rows x 64), waves 0..3
        if (wv < 4) {
            const float* s = hok ? (isrc + (size_t)(cc * 4 + wv) * 4096) : zsrc;
            gl16(s, &Ib[buf][wv * 256]);
        }
    };

    float acc[8][4], accc[8][4];
#pragma unroll
    for (int i = 0; i < 8; ++i)
#pragma unroll
        for (int j = 0; j < 4; ++j) { acc[i][j] = 0.f; accc[i][j] = 0.f; }

    stage(0, 0);
    __syncthreads();

    for (int cc = 0; cc < 256; ++cc) {
        const int buf = cc & 1;
        if (cc + 1 < 256) stage(cc + 1, buf ^ 1);

#pragma unroll
        for (int c = 0; c < 4; ++c) {
            const float* irow = &Ib[buf][c * 256];
            const float* wbase = &Wb[buf][c * 9 * 128 + ty * 8];
#pragma unroll
            for (int kh = 0; kh < 3; ++kh) {
                const float* row = irow + (hloc + kh) * 64;
                float4 v0 = *(const float4*)(row + w0i);
                float xl = (tx == 0) ? 0.f : row[w0i - 1];
                float xrr = (tx == 15) ? 0.f : row[w0i + 4];
                float xr[6];
                xr[0] = xl; xr[1] = v0.x; xr[2] = v0.y; xr[3] = v0.z; xr[4] = v0.w;
                xr[5] = xrr;
#pragma unroll
                for (int kw = 0; kw < 3; ++kw) {
                    const float* wr = wbase + (kh * 3 + kw) * 128;
                    float4 wa = *(const float4*)wr;
                    float4 wb2 = *(const float4*)(wr + 4);
#pragma unroll
                    for (int jw = 0; jw < 4; ++jw) {
                        float xv = xr[kw + jw];
                        accc[0][jw] += wa.x * xv;
                        accc[1][jw] += wa.y * xv;
                        accc[2][jw] += wa.z * xv;
                        accc[3][jw] += wa.w * xv;
                        accc[4][jw] += wb2.x * xv;
                        accc[5][jw] += wb2.y * xv;
                        accc[6][jw] += wb2.z * xv;
                        accc[7][jw] += wb2.w * xv;
                    }
                }
            }
        }
        if (cc & 1) {   // fold every 8 channels (bitwise-identical to R0/R2 order)
#pragma unroll
            for (int i = 0; i < 8; ++i)
#pragma unroll
                for (int j = 0; j < 4; ++j) { acc[i][j] += accc[i][j]; accc[i][j] = 0.f; }
        }
        __syncthreads();
    }

    const int h = h0 + hloc;
#pragma unroll
    for (int i = 0; i < 8; ++i) {
        int o = ot * 128 + ty * 8 + i;
        float bias = bc[o];
        float4 r0;
        r0.x = fmaxf(acc[i][0] + bias, 0.f);
        r0.y = fmaxf(acc[i][1] + bias, 0.f);
        r0.z = fmaxf(acc[i][2] + bias, 0.f);
        r0.w = fmaxf(acc[i][3] + bias, 0.f);
        size_t off = (((size_t)(b * 512 + o) * 64) + h) * 64 + w0i;
        *(float4*)&xout[off] = r0;
    }
}

// ---------------- heads: 1x1 convs + softmax + decode + clip + filter ----------------
__global__ __launch_bounds__(256) void head_kernel(
    const float* __restrict__ x, const float* __restrict__ Wcls,
    const float* __restrict__ bcls, const float* __restrict__ Wbb,
    const float* __restrict__ bbb, const float* __restrict__ meta,
    ull* __restrict__ keys, float4* __restrict__ boxes)
{
    __shared__ __align__(16) float Wl[512 * 20]; // [c][j], 40 KB
    const int b = blockIdx.y, blk = blockIdx.x, tid = threadIdx.x;

#pragma unroll
    for (int r = 0; r < 40; ++r) {
        int L = tid + 256 * r;               // 0..10239
        int c = L / 20, j = L - 20 * c;
        Wl[c * 20 + j] = (j < 4) ? Wcls[j * 512 + c] : Wbb[(j - 4) * 512 + c];
    }
    __syncthreads();

    const int p = blk * 256 + tid;           // spatial position 0..4095
    const float* xb = x + (size_t)(b * 512) * 4096 + p;

    float acc[20];
#pragma unroll
    for (int j = 0; j < 20; ++j) acc[j] = 0.f;

    for (int c0 = 0; c0 < 512; c0 += 64) {
        float at[20];
#pragma unroll
        for (int j = 0; j < 20; ++j) at[j] = 0.f;
        for (int c = c0; c < c0 + 64; ++c) {
            float xv = xb[(size_t)c * 4096];
            const float4* wr = (const float4*)(Wl + c * 20);
            float4 w0 = wr[0], w1 = wr[1], w2 = wr[2], w3 = wr[3], w4 = wr[4];
            at[0] += w0.x * xv;  at[1] += w0.y * xv;  at[2] += w0.z * xv;  at[3] += w0.w * xv;
            at[4] += w1.x * xv;  at[5] += w1.y * xv;  at[6] += w1.z * xv;  at[7] += w1.w * xv;
            at[8] += w2.x * xv;  at[9] += w2.y * xv;  at[10] += w2.z * xv; at[11] += w2.w * xv;
            at[12] += w3.x * xv; at[13] += w3.y * xv; at[14] += w3.z * xv; at[15] += w3.w * xv;
            at[16] += w4.x * xv; at[17] += w4.y * xv; at[18] += w4.z * xv; at[19] += w4.w * xv;
        }
#pragma unroll
        for (int j = 0; j < 20; ++j) acc[j] += at[j];
    }

    float s[4], d[16];
#pragma unroll
    for (int j = 0; j < 4; ++j) s[j] = acc[j] + bcls[j];
#pragma unroll
    for (int j = 0; j < 16; ++j) d[j] = acc[4 + j] + bbb[j];

    float prob[4];
#pragma unroll
    for (int pr = 0; pr < 2; ++pr) {
        float m = fmaxf(s[pr], s[pr + 2]);
        float e0 = expf(s[pr] - m), e2 = expf(s[pr + 2] - m);
        float sum = e0 + e2;
        prob[pr] = e0 / sum;
        prob[pr + 2] = e2 / sum;
    }

    const float imh1 = meta[b * 3 + 0] - 1.0f;
    const float imw1 = meta[b * 3 + 1] - 1.0f;
    const float minsz = 16.0f * meta[b * 3 + 2];
    const int wp = p & 63, hp = p >> 6;
    const float cx = (float)(wp * 16 + 8), cy = (float)(hp * 16 + 8);

#pragma unroll
    for (int a = 0; a < 4; ++a) {
        float wa = (float)(64 << a);
        float pcx = d[4 * a + 0] * wa + cx;
        float pcy = d[4 * a + 1] * wa + cy;
        float pw = expf(d[4 * a + 2]) * wa;
        float ph = expf(d[4 * a + 3]) * wa;
        float x1 = pcx - 0.5f * pw, y1 = pcy - 0.5f * ph;
        float x2 = pcx + 0.5f * pw, y2 = pcy + 0.5f * ph;
        x1 = fminf(fmaxf(x1, 0.f), imw1);
        y1 = fminf(fmaxf(y1, 0.f), imh1);
        x2 = fminf(fmaxf(x2, 0.f), imw1);
        y2 = fminf(fmaxf(y2, 0.f), imh1);
        bool keep = (((x2 - x1) + 1.0f) >= minsz) && (((y2 - y1) + 1.0f) >= minsz);
        float sc = keep ? prob[a] : -__builtin_inff();
        int n = p * 4 + a;
        keys[b * 16384 + n] = ((ull)ordf(sc) << 32) | (ull)(unsigned)(16383 - n);
        float4 bx; bx.x = x1; bx.y = y1; bx.z = x2; bx.w = y2;
        boxes[b * 16384 + n] = bx;
    }
}

// ---------------- bitonic sort (descending) over uint64 keys ----------------
__global__ __launch_bounds__(512) void sort_local(ull* __restrict__ keys, int kfirst, int klast)
{
    __shared__ ull s[4096];
    const int b = blockIdx.y, chunk = blockIdx.x, tid = threadIdx.x;
    ull* g = keys + b * 16384 + chunk * 4096;
#pragma unroll
    for (int r = 0; r < 8; ++r) s[tid + 512 * r] = g[tid + 512 * r];
    __syncthreads();
    const int gbase = chunk * 4096;
    for (int k = kfirst; k <= klast; k <<= 1) {
        int j0 = (k >> 1) < 2048 ? (k >> 1) : 2048;
        for (int j = j0; j > 0; j >>= 1) {
#pragma unroll
            for (int pp = 0; pp < 4; ++pp) {
                int p = tid + 512 * pp;
                int i = ((p & ~(j - 1)) << 1) | (p & (j - 1));
                int l = i + j;
                ull a = s[i], c = s[l];
                bool up = (((gbase + i) & k) == 0);
                bool sw = up ? (a < c) : (c < a);
                if (sw) { s[i] = c; s[l] = a; }
            }
            __syncthreads();
        }
    }
#pragma unroll
    for (int r = 0; r < 8; ++r) g[tid + 512 * r] = s[tid + 512 * r];
}

__global__ __launch_bounds__(256) void sort_global_k(ull* __restrict__ keys, int k, int j)
{
    int t = blockIdx.x * 256 + threadIdx.x;
    int b = t >> 13, p = t & 8191;
    int i = ((p & ~(j - 1)) << 1) | (p & (j - 1));
    int l = i + j;
    ull* g = keys + b * 16384;
    ull a = g[i], c = g[l];
    bool up = ((i & k) == 0);
    bool sw = up ? (a < c) : (c < a);
    if (sw) { g[i] = c; g[l] = a; }
}

// ---------------- gather top-6000 sorted boxes ----------------
__global__ __launch_bounds__(256) void gather_kernel(
    const ull* __restrict__ keys, const float4* __restrict__ boxes,
    float4* __restrict__ bs, float* __restrict__ as_, ull* __restrict__ valid)
{
    const int b = blockIdx.y;
    const int i = blockIdx.x * 256 + threadIdx.x;
    bool fin = false;
    float4 box; box.x = 0.f; box.y = 0.f; box.z = 0.f; box.w = 0.f;
    float area = 1.f;
    if (i < 6000) {
        ull k = keys[b * 16384 + i];
        fin = ((unsigned)(k >> 32)) != NEGINF_ORD;
        int idx = 16383 - (int)(k & 0xFFFFFFFFull);
        box = boxes[b * 16384 + idx];
        area = ((box.z - box.x) + 1.0f) * ((box.w - box.y) + 1.0f);
    }
    bs[b * 6144 + i] = box;
    as_[b * 6144 + i] = area;
    ull m = __ballot(fin ? 1 : 0);
    if ((threadIdx.x & 63) == 0) valid[b * 96 + (i >> 6)] = m;
}

// ---------------- sequential greedy NMS with bitmask head scan ----------------
__global__ __launch_bounds__(1024) void nms_kernel(
    const float4* __restrict__ bs, const float* __restrict__ as_,
    const ull* __restrict__ valid, float* __restrict__ out)
{
    __shared__ unsigned alive[192];    // 6144 bits
    __shared__ int keepL[300];
    __shared__ int jsh;
    __shared__ int cur_sh;

    const int b = blockIdx.x, tid = threadIdx.x;

    if (tid < 96) {
        ull w = valid[b * 96 + tid];
        alive[tid * 2] = (unsigned)w;
        alive[tid * 2 + 1] = (unsigned)(w >> 32);
    }
    if (tid == 0) cur_sh = 0;
    __syncthreads();

    float4 box[6]; float area[6]; bool sf[6];
#pragma unroll
    for (int q = 0; q < 6; ++q) {
        int i = tid * 6 + q;
        box[q] = bs[b * 6144 + i];
        area[q] = as_[b * 6144 + i];
        sf[q] = !((alive[i >> 5] >> (i & 31)) & 1u);
    }
    __syncthreads();

    for (int t = 0; t < 300; ++t) {
        if (tid == 0) {
            int w = cur_sh;
            unsigned v = 0;
            while (w < 192 && (v = alive[w]) == 0u) ++w;
            int j;
            if (w < 192) {
                int bit = __ffs(v) - 1;
                j = w * 32 + bit;
                alive[w] = v & (v - 1);   // consume j
            } else {
                j = 0;
            }
            cur_sh = w;
            jsh = j; keepL[t] = j;
        }
        __syncthreads();
        const int j = jsh;
        const float4 jb = bs[b * 6144 + j];     // broadcast load, L1-cached
        const float ja = as_[b * 6144 + j];
#pragma unroll
        for (int q = 0; q < 6; ++q) {
            int i = tid * 6 + q;
            if (i == j) sf[q] = true;
            if (!sf[q] && i > j) {
                float xx1 = fmaxf(jb.x, box[q].x);
                float yy1 = fmaxf(jb.y, box[q].y);
                float xx2 = fminf(jb.z, box[q].z);
                float yy2 = fminf(jb.w, box[q].w);
                float iw = fmaxf((xx2 - xx1) + 1.0f, 0.f);
                float ih = fmaxf((yy2 - yy1) + 1.0f, 0.f);
                float inter = iw * ih;
                float iou = inter / ((ja + area[q]) - inter);
                if (iou > 0.7f) {
                    sf[q] = true;
                    atomicAnd(&alive[i >> 5], ~(1u << (i & 31)));
                }
            }
        }
        __syncthreads();
    }

    if (tid < 300) {
        int j = keepL[tid];
        float4 bx = bs[b * 6144 + j];
        float* o = out + (size_t)(b * 300 + tid) * 5;
        o[0] = (float)b; o[1] = bx.x; o[2] = bx.y; o[3] = bx.z; o[4] = bx.w;
    }
}

// ---------------- launcher ----------------
extern "C" void kernel_launch(void* const* d_in, const int* in_sizes, int n_in,
                              void* d_out, int out_size, void* d_ws, size_t ws_size,
                              hipStream_t stream) {
    const float* feat  = (const float*)d_in[0];
    const float* meta  = (const float*)d_in[1];
    const float* Wconv = (const float*)d_in[3];
    const float* bconv = (const float*)d_in[4];
    const float* Wcls  = (const float*)d_in[5];
    const float* bcls  = (const float*)d_in[6];
    const float* Wbb   = (const float*)d_in[7];
    const float* bbb   = (const float*)d_in[8];
    float* out = (float*)d_out;

    char* ws = (char*)d_ws;
    float*  x     = (float*)(ws);                       // 16,777,216 B
    float*  Wt2   = (float*)(ws + 16777216);            // 18,874,368 B
    float*  zerop = (float*)(ws + 35651584);            //      4,096 B
    ull*    keys  = (ull*)(ws + 35655680);              //    262,144 B
    float4* boxes = (float4*)(ws + 35917824);           //  1,048,576 B
    float4* bsort = (float4*)(ws + 36966400);           //    196,608 B
    float*  asort = (float*)(ws + 37163008);            //     49,152 B
    ull*    valid = (ull*)(ws + 37212160);              //      1,536 B

    zero_fill<<<1, 256, 0, stream>>>(zerop);
    reorder_w<<<dim3(576, 4), 256, 0, stream>>>(Wconv, Wt2);
    conv3x3_kernel<<<dim3(32, 4, 2), 512, 0, stream>>>(Wt2, feat, zerop, bconv, x);
    head_kernel<<<dim3(16, 2), 256, 0, stream>>>(x, Wcls, bcls, Wbb, bbb, meta, keys, boxes);
    sort_local<<<dim3(4, 2), 512, 0, stream>>>(keys, 2, 4096);
    sort_global_k<<<64, 256, 0, stream>>>(keys, 8192, 4096);
    sort_local<<<dim3(4, 2), 512, 0, stream>>>(keys, 8192, 8192);
    sort_global_k<<<64, 256, 0, stream>>>(keys, 16384, 8192);
    sort_global_k<<<64, 256, 0, stream>>>(keys, 16384, 4096);
    sort_local<<<dim3(4, 2), 512, 0, stream>>>(keys, 16384, 16384);
    gather_kernel<<<dim3(24, 2), 256, 0, stream>>>(keys, boxes, bsort, asort, valid);
    nms_kernel<<<2, 1024, 0, stream>>>(bsort, asort, valid, out);
}

// Round 9
// 2638.679 us; speedup vs baseline: 3.2916x; 3.2916x over previous
//
#include <hip/hip_runtime.h>
#include <stdint.h>

typedef unsigned long long ull;

#define NEGINF_ORD 0x007FFFFFu

__device__ __forceinline__ unsigned ordf(float f) {
    unsigned u = __float_as_uint(f);
    return (u & 0x80000000u) ? ~u : (u | 0x80000000u);
}

__device__ __forceinline__ void gl16(const float* g, float* l) {
    __builtin_amdgcn_global_load_lds(
        (const __attribute__((address_space(1))) unsigned*)g,
        (__attribute__((address_space(3))) unsigned*)l, 16, 0, 0);
}

// ---------------- tiny prepass kernels ----------------
__global__ __launch_bounds__(256) void zero_fill(float* __restrict__ z) {
    z[threadIdx.x] = 0.f;   // 1KB zero page (256 floats)
}

// W [512][1024][3][3] -> Wt2[ot=8][k=9216][o=64]  (k = c*9 + kh*3 + kw)
__global__ __launch_bounds__(256) void reorder_w(const float* __restrict__ W, float* __restrict__ Wt2) {
    __shared__ float t[16][65];
    const int kb = blockIdx.x * 16;      // 576
    const int ot = blockIdx.y;           // 8
    const int tid = threadIdx.x;
#pragma unroll
    for (int r = 0; r < 4; ++r) {
        int e = tid + 256 * r;           // 0..1023
        int o_l = e >> 4, kk = e & 15;
        t[kk][o_l] = W[(size_t)(ot * 64 + o_l) * 9216 + kb + kk];
    }
    __syncthreads();
#pragma unroll
    for (int r = 0; r < 4; ++r) {
        int e = tid + 256 * r;
        int kk = e >> 6, o_l = e & 63;
        Wt2[((size_t)ot * 9216 + kb + kk) * 64 + o_l] = t[kk][o_l];
    }
}

// ---------------- conv 3x3 + bias + relu ----------------
// tile: O=64, H=2, W=64. 256 thr: tx=tid&15 (w=tx*4), hloc=(tid>>4)&1, ty=tid>>5 (o=ty*8, 0..7)
// LDS: Wb[2][36k][64o] (18KB) + Ib[2][4c][4r][64w] (8KB) = 26KB, CK=4 double buffered.
// 256 thr/block: under the observed "2 workgroups/CU = 65536 VGPR/wg" allocator
// heuristic (R2 vs R3/R4/R8 evidence), cap = 256 VGPR/thread; ~110-reg working
// set fits -> no spill. 512-thr variants capped at 128 and spilled 21 GB/dispatch.
__global__ __launch_bounds__(256) void conv3x3_kernel(
    const float* __restrict__ Wt2, const float* __restrict__ in,
    const float* __restrict__ zerop, const float* __restrict__ bc,
    float* __restrict__ xout)
{
    __shared__ __align__(16) float Wb[2][36 * 64];
    __shared__ __align__(16) float Ib[2][4 * 4 * 64];

    const int h0 = blockIdx.x * 2;
    const int ot = blockIdx.y;      // 0..7 (64 outputs each)
    const int b  = blockIdx.z;
    const int tid = threadIdx.x;
    const int tx = tid & 15;
    const int hloc = (tid >> 4) & 1;
    const int ty = tid >> 5;        // 0..7
    const int wv = tid >> 6;        // wave 0..3
    const int ln = tid & 63;
    const int w0i = tx * 4;

    // staging lane mapping (per-lane global addr; hok=false lanes -> zero page)
    const int r_ln = ln >> 4;               // 0..3
    const int wc_ln = (ln & 15) * 4;
    const int hin = h0 - 1 + r_ln;
    const bool hok = (hin >= 0) && (hin < 64);
    const float* isrc = in + ((size_t)(b * 1024) * 64 + (hok ? hin : 0)) * 64 + wc_ln;
    const float* zsrc = zerop + ln * 4;
    const float* wsrc = Wt2 + (size_t)ot * 9216 * 64 + ln * 4;

    auto stage = [&](int cc, int buf) {
        // weights: 9 x 1KB wave-DMAs (4 k-rows of 64 each), split over 4 waves
        const float* wsB = wsrc + (size_t)cc * 36 * 64;
#pragma unroll
        for (int j = 0; j < 3; ++j) {
            int m = wv + 4 * j;
            if (m < 9)
                gl16(wsB + (size_t)m * 256, &Wb[buf][m * 256]);
        }
        // input: 4 channels, one 1KB wave-DMA each (4 rows x 64), one per wave
        const float* s = hok ? (isrc + (size_t)(cc * 4 + wv) * 4096) : zsrc;
        gl16(s, &Ib[buf][wv * 256]);
    };

    float acc[8][4], accc[8][4];
#pragma unroll
    for (int i = 0; i < 8; ++i)
#pragma unroll
        for (int j = 0; j < 4; ++j) { acc[i][j] = 0.f; accc[i][j] = 0.f; }

    stage(0, 0);
    __syncthreads();

    for (int cc = 0; cc < 256; ++cc) {
        const int buf = cc & 1;
        if (cc + 1 < 256) stage(cc + 1, buf ^ 1);

#pragma unroll
        for (int c = 0; c < 4; ++c) {
            const float* irow = &Ib[buf][c * 256];
            const float* wbase = &Wb[buf][c * 9 * 64 + ty * 8];
#pragma unroll
            for (int kh = 0; kh < 3; ++kh) {
                const float* row = irow + (hloc + kh) * 64;
                float4 v0 = *(const float4*)(row + w0i);
                float xl = (tx == 0) ? 0.f : row[w0i - 1];
                float xrr = (tx == 15) ? 0.f : row[w0i + 4];
                float xr[6];
                xr[0] = xl; xr[1] = v0.x; xr[2] = v0.y; xr[3] = v0.z; xr[4] = v0.w;
                xr[5] = xrr;
#pragma unroll
                for (int kw = 0; kw < 3; ++kw) {
                    const float* wr = wbase + (kh * 3 + kw) * 64;
                    float4 wa = *(const float4*)wr;
                    float4 wb2 = *(const float4*)(wr + 4);
#pragma unroll
                    for (int jw = 0; jw < 4; ++jw) {
                        float xv = xr[kw + jw];
                        accc[0][jw] += wa.x * xv;
                        accc[1][jw] += wa.y * xv;
                        accc[2][jw] += wa.z * xv;
                        accc[3][jw] += wa.w * xv;
                        accc[4][jw] += wb2.x * xv;
                        accc[5][jw] += wb2.y * xv;
                        accc[6][jw] += wb2.z * xv;
                        accc[7][jw] += wb2.w * xv;
                    }
                }
            }
        }
        if (cc & 1) {   // fold every 8 channels (bitwise-identical to R0/R2 order)
#pragma unroll
            for (int i = 0; i < 8; ++i)
#pragma unroll
                for (int j = 0; j < 4; ++j) { acc[i][j] += accc[i][j]; accc[i][j] = 0.f; }
        }
        __syncthreads();
    }

    const int h = h0 + hloc;
#pragma unroll
    for (int i = 0; i < 8; ++i) {
        int o = ot * 64 + ty * 8 + i;
        float bias = bc[o];
        float4 r0;
        r0.x = fmaxf(acc[i][0] + bias, 0.f);
        r0.y = fmaxf(acc[i][1] + bias, 0.f);
        r0.z = fmaxf(acc[i][2] + bias, 0.f);
        r0.w = fmaxf(acc[i][3] + bias, 0.f);
        size_t off = (((size_t)(b * 512 + o) * 64) + h) * 64 + w0i;
        *(float4*)&xout[off] = r0;
    }
}

// ---------------- heads: 1x1 convs + softmax + decode + clip + filter ----------------
__global__ __launch_bounds__(256) void head_kernel(
    const float* __restrict__ x, const float* __restrict__ Wcls,
    const float* __restrict__ bcls, const float* __restrict__ Wbb,
    const float* __restrict__ bbb, const float* __restrict__ meta,
    ull* __restrict__ keys, float4* __restrict__ boxes)
{
    __shared__ __align__(16) float Wl[512 * 20]; // [c][j], 40 KB
    const int b = blockIdx.y, blk = blockIdx.x, tid = threadIdx.x;

#pragma unroll
    for (int r = 0; r < 40; ++r) {
        int L = tid + 256 * r;               // 0..10239
        int c = L / 20, j = L - 20 * c;
        Wl[c * 20 + j] = (j < 4) ? Wcls[j * 512 + c] : Wbb[(j - 4) * 512 + c];
    }
    __syncthreads();

    const int p = blk * 256 + tid;           // spatial position 0..4095
    const float* xb = x + (size_t)(b * 512) * 4096 + p;

    float acc[20];
#pragma unroll
    for (int j = 0; j < 20; ++j) acc[j] = 0.f;

    for (int c0 = 0; c0 < 512; c0 += 64) {
        float at[20];
#pragma unroll
        for (int j = 0; j < 20; ++j) at[j] = 0.f;
        for (int c = c0; c < c0 + 64; ++c) {
            float xv = xb[(size_t)c * 4096];
            const float4* wr = (const float4*)(Wl + c * 20);
            float4 w0 = wr[0], w1 = wr[1], w2 = wr[2], w3 = wr[3], w4 = wr[4];
            at[0] += w0.x * xv;  at[1] += w0.y * xv;  at[2] += w0.z * xv;  at[3] += w0.w * xv;
            at[4] += w1.x * xv;  at[5] += w1.y * xv;  at[6] += w1.z * xv;  at[7] += w1.w * xv;
            at[8] += w2.x * xv;  at[9] += w2.y * xv;  at[10] += w2.z * xv; at[11] += w2.w * xv;
            at[12] += w3.x * xv; at[13] += w3.y * xv; at[14] += w3.z * xv; at[15] += w3.w * xv;
            at[16] += w4.x * xv; at[17] += w4.y * xv; at[18] += w4.z * xv; at[19] += w4.w * xv;
        }
#pragma unroll
        for (int j = 0; j < 20; ++j) acc[j] += at[j];
    }

    float s[4], d[16];
#pragma unroll
    for (int j = 0; j < 4; ++j) s[j] = acc[j] + bcls[j];
#pragma unroll
    for (int j = 0; j < 16; ++j) d[j] = acc[4 + j] + bbb[j];

    float prob[4];
#pragma unroll
    for (int pr = 0; pr < 2; ++pr) {
        float m = fmaxf(s[pr], s[pr + 2]);
        float e0 = expf(s[pr] - m), e2 = expf(s[pr + 2] - m);
        float sum = e0 + e2;
        prob[pr] = e0 / sum;
        prob[pr + 2] = e2 / sum;
    }

    const float imh1 = meta[b * 3 + 0] - 1.0f;
    const float imw1 = meta[b * 3 + 1] - 1.0f;
    const float minsz = 16.0f * meta[b * 3 + 2];
    const int wp = p & 63, hp = p >> 6;
    const float cx = (float)(wp * 16 + 8), cy = (float)(hp * 16 + 8);

#pragma unroll
    for (int a = 0; a < 4; ++a) {
        float wa = (float)(64 << a);
        float pcx = d[4 * a + 0] * wa + cx;
        float pcy = d[4 * a + 1] * wa + cy;
        float pw = expf(d[4 * a + 2]) * wa;
        float ph = expf(d[4 * a + 3]) * wa;
        float x1 = pcx - 0.5f * pw, y1 = pcy - 0.5f * ph;
        float x2 = pcx + 0.5f * pw, y2 = pcy + 0.5f * ph;
        x1 = fminf(fmaxf(x1, 0.f), imw1);
        y1 = fminf(fmaxf(y1, 0.f), imh1);
        x2 = fminf(fmaxf(x2, 0.f), imw1);
        y2 = fminf(fmaxf(y2, 0.f), imh1);
        bool keep = (((x2 - x1) + 1.0f) >= minsz) && (((y2 - y1) + 1.0f) >= minsz);
        float sc = keep ? prob[a] : -__builtin_inff();
        int n = p * 4 + a;
        keys[b * 16384 + n] = ((ull)ordf(sc) << 32) | (ull)(unsigned)(16383 - n);
        float4 bx; bx.x = x1; bx.y = y1; bx.z = x2; bx.w = y2;
        boxes[b * 16384 + n] = bx;
    }
}

// ---------------- bitonic sort (descending) over uint64 keys ----------------
__global__ __launch_bounds__(512) void sort_local(ull* __restrict__ keys, int kfirst, int klast)
{
    __shared__ ull s[4096];
    const int b = blockIdx.y, chunk = blockIdx.x, tid = threadIdx.x;
    ull* g = keys + b * 16384 + chunk * 4096;
#pragma unroll
    for (int r = 0; r < 8; ++r) s[tid + 512 * r] = g[tid + 512 * r];
    __syncthreads();
    const int gbase = chunk * 4096;
    for (int k = kfirst; k <= klast; k <<= 1) {
        int j0 = (k >> 1) < 2048 ? (k >> 1) : 2048;
        for (int j = j0; j > 0; j >>= 1) {
#pragma unroll
            for (int pp = 0; pp < 4; ++pp) {
                int p = tid + 512 * pp;
                int i = ((p & ~(j - 1)) << 1) | (p & (j - 1));
                int l = i + j;
                ull a = s[i], c = s[l];
                bool up = (((gbase + i) & k) == 0);
                bool sw = up ? (a < c) : (c < a);
                if (sw) { s[i] = c; s[l] = a; }
            }
            __syncthreads();
        }
    }
#pragma unroll
    for (int r = 0; r < 8; ++r) g[tid + 512 * r] = s[tid + 512 * r];
}

__global__ __launch_bounds__(256) void sort_global_k(ull* __restrict__ keys, int k, int j)
{
    int t = blockIdx.x * 256 + threadIdx.x;
    int b = t >> 13, p = t & 8191;
    int i = ((p & ~(j - 1)) << 1) | (p & (j - 1));
    int l = i + j;
    ull* g = keys + b * 16384;
    ull a = g[i], c = g[l];
    bool up = ((i & k) == 0);
    bool sw = up ? (a < c) : (c < a);
    if (sw) { g[i] = c; g[l] = a; }
}

// ---------------- gather top-6000 sorted boxes ----------------
__global__ __launch_bounds__(256) void gather_kernel(
    const ull* __restrict__ keys, const float4* __restrict__ boxes,
    float4* __restrict__ bs, float* __restrict__ as_, ull* __restrict__ valid)
{
    const int b = blockIdx.y;
    const int i = blockIdx.x * 256 + threadIdx.x;
    bool fin = false;
    float4 box; box.x = 0.f; box.y = 0.f; box.z = 0.f; box.w = 0.f;
    float area = 1.f;
    if (i < 6000) {
        ull k = keys[b * 16384 + i];
        fin = ((unsigned)(k >> 32)) != NEGINF_ORD;
        int idx = 16383 - (int)(k & 0xFFFFFFFFull);
        box = boxes[b * 16384 + idx];
        area = ((box.z - box.x) + 1.0f) * ((box.w - box.y) + 1.0f);
    }
    bs[b * 6144 + i] = box;
    as_[b * 6144 + i] = area;
    ull m = __ballot(fin ? 1 : 0);
    if ((threadIdx.x & 63) == 0) valid[b * 96 + (i >> 6)] = m;
}

// ---------------- sequential greedy NMS with bitmask head scan ----------------
__global__ __launch_bounds__(1024) void nms_kernel(
    const float4* __restrict__ bs, const float* __restrict__ as_,
    const ull* __restrict__ valid, float* __restrict__ out)
{
    __shared__ unsigned alive[192];    // 6144 bits
    __shared__ int keepL[300];
    __shared__ int jsh;
    __shared__ int cur_sh;

    const int b = blockIdx.x, tid = threadIdx.x;

    if (tid < 96) {
        ull w = valid[b * 96 + tid];
        alive[tid * 2] = (unsigned)w;
        alive[tid * 2 + 1] = (unsigned)(w >> 32);
    }
    if (tid == 0) cur_sh = 0;
    __syncthreads();

    float4 box[6]; float area[6]; bool sf[6];
#pragma unroll
    for (int q = 0; q < 6; ++q) {
        int i = tid * 6 + q;
        box[q] = bs[b * 6144 + i];
        area[q] = as_[b * 6144 + i];
        sf[q] = !((alive[i >> 5] >> (i & 31)) & 1u);
    }
    __syncthreads();

    for (int t = 0; t < 300; ++t) {
        if (tid == 0) {
            int w = cur_sh;
            unsigned v = 0;
            while (w < 192 && (v = alive[w]) == 0u) ++w;
            int j;
            if (w < 192) {
                int bit = __ffs(v) - 1;
                j = w * 32 + bit;
                alive[w] = v & (v - 1);   // consume j
            } else {
                j = 0;
            }
            cur_sh = w;
            jsh = j; keepL[t] = j;
        }
        __syncthreads();
        const int j = jsh;
        const float4 jb = bs[b * 6144 + j];     // broadcast load, L1-cached
        const float ja = as_[b * 6144 + j];
#pragma unroll
        for (int q = 0; q < 6; ++q) {
            int i = tid * 6 + q;
            if (i == j) sf[q] = true;
            if (!sf[q] && i > j) {
                float xx1 = fmaxf(jb.x, box[q].x);
                float yy1 = fmaxf(jb.y, box[q].y);
                float xx2 = fminf(jb.z, box[q].z);
                float yy2 = fminf(jb.w, box[q].w);
                float iw = fmaxf((xx2 - xx1) + 1.0f, 0.f);
                float ih = fmaxf((yy2 - yy1) + 1.0f, 0.f);
                float inter = iw * ih;
                float iou = inter / ((ja + area[q]) - inter);
                if (iou > 0.7f) {
                    sf[q] = true;
                    atomicAnd(&alive[i >> 5], ~(1u << (i & 31)));
                }
            }
        }
        __syncthreads();
    }

    if (tid < 300) {
        int j = keepL[tid];
        float4 bx = bs[b * 6144 + j];
        float* o = out + (size_t)(b * 300 + tid) * 5;
        o[0] = (float)b; o[1] = bx.x; o[2] = bx.y; o[3] = bx.z; o[4] = bx.w;
    }
}

// ---------------- launcher ----------------
extern "C" void kernel_launch(void* const* d_in, const int* in_sizes, int n_in,
                              void* d_out, int out_size, void* d_ws, size_t ws_size,
                              hipStream_t stream) {
    const float* feat  = (const float*)d_in[0];
    const float* meta  = (const float*)d_in[1];
    const float* Wconv = (const float*)d_in[3];
    const float* bconv = (const float*)d_in[4];
    const float* Wcls  = (const float*)d_in[5];
    const float* bcls  = (const float*)d_in[6];
    const float* Wbb   = (const float*)d_in[7];
    const float* bbb   = (const float*)d_in[8];
    float* out = (float*)d_out;

    char* ws = (char*)d_ws;
    float*  x     = (float*)(ws);                       // 16,777,216 B
    float*  Wt2   = (float*)(ws + 16777216);            // 18,874,368 B
    float*  zerop = (float*)(ws + 35651584);            //      4,096 B
    ull*    keys  = (ull*)(ws + 35655680);              //    262,144 B
    float4* boxes = (float4*)(ws + 35917824);           //  1,048,576 B
    float4* bsort = (float4*)(ws + 36966400);           //    196,608 B
    float*  asort = (float*)(ws + 37163008);            //     49,152 B
    ull*    valid = (ull*)(ws + 37212160);              //      1,536 B

    zero_fill<<<1, 256, 0, stream>>>(zerop);
    reorder_w<<<dim3(576, 8), 256, 0, stream>>>(Wconv, Wt2);
    conv3x3_kernel<<<dim3(32, 8, 2), 256, 0, stream>>>(Wt2, feat, zerop, bconv, x);
    head_kernel<<<dim3(16, 2), 256, 0, stream>>>(x, Wcls, bcls, Wbb, bbb, meta, keys, boxes);
    sort_local<<<dim3(4, 2), 512, 0, stream>>>(keys, 2, 4096);
    sort_global_k<<<64, 256, 0, stream>>>(keys, 8192, 4096);
    sort_local<<<dim3(4, 2), 512, 0, stream>>>(keys, 8192, 8192);
    sort_global_k<<<64, 256, 0, stream>>>(keys, 16384, 8192);
    sort_global_k<<<64, 256, 0, stream>>>(keys, 16384, 4096);
    sort_local<<<dim3(4, 2), 512, 0, stream>>>(keys, 16384, 16384);
    gather_kernel<<<dim3(24, 2), 256, 0, stream>>>(keys, boxes, bsort, asort, valid);
    nms_kernel<<<2, 1024, 0, stream>>>(bsort, asort, valid, out);
}

// Round 11
// 2466.778 us; speedup vs baseline: 3.5209x; 1.0697x over previous
//
#include <hip/hip_runtime.h>
#include <stdint.h>

typedef unsigned long long ull;

#define NEGINF_ORD 0x007FFFFFu

__device__ __forceinline__ unsigned ordf(float f) {
    unsigned u = __float_as_uint(f);
    return (u & 0x80000000u) ? ~u : (u | 0x80000000u);
}

__device__ __forceinline__ void gl16(const float* g, float* l) {
    __builtin_amdgcn_global_load_lds(
        (const __attribute__((address_space(1))) unsigned*)g,
        (__attribute__((address_space(3))) unsigned*)l, 16, 0, 0);
}

// ---------------- tiny prepass kernels ----------------
__global__ __launch_bounds__(256) void zero_fill(float* __restrict__ z) {
    z[threadIdx.x] = 0.f;   // 1KB zero page (256 floats)
}

// W [512][1024][3][3] -> Wt3[ot=16][c=1024][wv=4][kk=9][i=8]
// (o = ot*32 + wv*8 + i ; k = kk = kh*3+kw). Per (c,wave): 72 contiguous floats.
__global__ __launch_bounds__(256) void reorder_w(const float* __restrict__ W, float* __restrict__ Wt3) {
    __shared__ float t[8][580];
    const int cb = blockIdx.x;   // 16 chunks of 64 channels
    const int wv = blockIdx.y;   // 4
    const int ot = blockIdx.z;   // 16
    const int tid = threadIdx.x;
    for (int e = tid; e < 8 * 576; e += 256) {        // 8 o-rows x (64c x 9k), coalesced
        int i = e / 576, k = e - i * 576;
        t[i][k] = W[(size_t)(ot * 32 + wv * 8 + i) * 9216 + cb * 576 + k];
    }
    __syncthreads();
    for (int e = tid; e < 4608; e += 256) {           // fully coalesced writes
        int cl = e / 72, r = e - cl * 72;
        int kk = r >> 3, i = r & 7;
        Wt3[((size_t)(ot * 1024 + cb * 64 + cl) * 4 + wv) * 72 + r] = t[i][cl * 9 + kk];
    }
}

// ---------------- conv 3x3 + bias + relu ----------------
// Block: 256 thr = 4 waves. Wave wv owns o-octet (o = ot*32+wv*8 .. +8) ->
// weight address is WAVE-UNIFORM -> s_load (SMEM pipe), consumed as SGPR
// operand of v_fmac. LDS holds input only (12 KB): per wave/cc 12 b128 + 24 b32
// vs R9's 84 b128 -> LDS pipe drops ~4x below the FMA wall (492 us floor).
// Lanes: tx=ln&15 (w=tx*4), hq=ln>>4 (4 h rows/block). Per-thread 8o x 4w.
// Accumulation order (c asc, kh, kw; fold accc->acc every 8 channels) is
// bitwise-identical to R9 (absmax 0.0 proven).
__global__ __launch_bounds__(256) void conv3x3_kernel(
    const float* __restrict__ Wt3, const float* __restrict__ in,
    const float* __restrict__ zerop, const float* __restrict__ bc,
    float* __restrict__ xout)
{
    __shared__ __align__(16) float Ib[2][4][6][64];   // [buf][c][row][w], 12 KB

    const int h0 = blockIdx.x * 4;
    const int ot = blockIdx.y;       // 32-o group
    const int b  = blockIdx.z;
    const int tid = threadIdx.x;
    const int wv = tid >> 6;
    const int ln = tid & 63;
    const int tx = ln & 15;
    const int hq = ln >> 4;          // 0..3
    const int w0i = tx * 4;
    const int wvu = __builtin_amdgcn_readfirstlane(wv);

    // wave-uniform weight base: index ((ot*1024 + c)*4 + wv)*72
    const float* wsg = Wt3 + ((size_t)ot * 4096 + wvu) * 72;
    const float* zsrc = zerop + ln * 4;

    auto stage = [&](int cc, int buf) {
        // 6 KB input (4 ch x 6 rows x 64): 6 wave-DMAs of 1KB, waves 0,1 do two
#pragma unroll
        for (int jj = 0; jj < 2; ++jj) {
            int j = wv + 4 * jj;
            if (j < 6) {
                int r = 4 * j + hq;              // 0..23
                int c = r / 6, rr = r - 6 * c;   // channel-local, row 0..5
                int hin = h0 - 1 + rr;
                bool ok = (hin >= 0) && (hin < 64);
                const float* s = ok
                    ? in + (((size_t)(b * 1024 + cc * 4 + c) * 64) + hin) * 64 + tx * 4
                    : zsrc;
                gl16(s, &Ib[buf][0][0][0] + j * 256);
            }
        }
    };

    float acc[8][4], accc[8][4];
#pragma unroll
    for (int i = 0; i < 8; ++i)
#pragma unroll
        for (int j = 0; j < 4; ++j) { acc[i][j] = 0.f; accc[i][j] = 0.f; }

    stage(0, 0);
    __syncthreads();

    for (int cc = 0; cc < 256; ++cc) {
        const int buf = cc & 1;
        if (cc + 1 < 256) stage(cc + 1, buf ^ 1);

#pragma unroll
        for (int ci = 0; ci < 4; ++ci) {
            const float* wc = wsg + (size_t)(cc * 4 + ci) * 288;  // this channel's 72 w
#pragma unroll
            for (int kh = 0; kh < 3; ++kh) {
                const float* rowp = &Ib[buf][ci][hq + kh][0];
                float4 v0 = *(const float4*)(rowp + w0i);
                float xl = (tx == 0) ? 0.f : rowp[w0i - 1];
                float xrr = (tx == 15) ? 0.f : rowp[w0i + 4];
                float xr[6];
                xr[0] = xl; xr[1] = v0.x; xr[2] = v0.y; xr[3] = v0.z; xr[4] = v0.w;
                xr[5] = xrr;
#pragma unroll
                for (int kw = 0; kw < 3; ++kw) {
                    const float* w8 = wc + (kh * 3 + kw) * 8;   // uniform -> SGPRs
#pragma unroll
                    for (int jw = 0; jw < 4; ++jw) {
                        float xv = xr[kw + jw];
                        accc[0][jw] += w8[0] * xv;
                        accc[1][jw] += w8[1] * xv;
                        accc[2][jw] += w8[2] * xv;
                        accc[3][jw] += w8[3] * xv;
                        accc[4][jw] += w8[4] * xv;
                        accc[5][jw] += w8[5] * xv;
                        accc[6][jw] += w8[6] * xv;
                        accc[7][jw] += w8[7] * xv;
                    }
                }
            }
        }
        if (cc & 1) {   // fold every 8 channels (bitwise-identical to R9)
#pragma unroll
            for (int i = 0; i < 8; ++i)
#pragma unroll
                for (int j = 0; j < 4; ++j) { acc[i][j] += accc[i][j]; accc[i][j] = 0.f; }
        }
        __syncthreads();
    }

    const int h = h0 + hq;
#pragma unroll
    for (int i = 0; i < 8; ++i) {
        int o = ot * 32 + wvu * 8 + i;
        float bias = bc[o];
        float4 r0;
        r0.x = fmaxf(acc[i][0] + bias, 0.f);
        r0.y = fmaxf(acc[i][1] + bias, 0.f);
        r0.z = fmaxf(acc[i][2] + bias, 0.f);
        r0.w = fmaxf(acc[i][3] + bias, 0.f);
        size_t off = (((size_t)(b * 512 + o) * 64) + h) * 64 + w0i;
        *(float4*)&xout[off] = r0;
    }
}

// ---------------- heads: 1x1 convs + softmax + decode + clip + filter ----------------
__global__ __launch_bounds__(256) void head_kernel(
    const float* __restrict__ x, const float* __restrict__ Wcls,
    const float* __restrict__ bcls, const float* __restrict__ Wbb,
    const float* __restrict__ bbb, const float* __restrict__ meta,
    ull* __restrict__ keys, float4* __restrict__ boxes)
{
    __shared__ __align__(16) float Wl[512 * 20]; // [c][j], 40 KB
    const int b = blockIdx.y, blk = blockIdx.x, tid = threadIdx.x;

#pragma unroll
    for (int r = 0; r < 40; ++r) {
        int L = tid + 256 * r;               // 0..10239
        int c = L / 20, j = L - 20 * c;
        Wl[c * 20 + j] = (j < 4) ? Wcls[j * 512 + c] : Wbb[(j - 4) * 512 + c];
    }
    __syncthreads();

    const int p = blk * 256 + tid;           // spatial position 0..4095
    const float* xb = x + (size_t)(b * 512) * 4096 + p;

    float acc[20];
#pragma unroll
    for (int j = 0; j < 20; ++j) acc[j] = 0.f;

    for (int c0 = 0; c0 < 512; c0 += 64) {
        float at[20];
#pragma unroll
        for (int j = 0; j < 20; ++j) at[j] = 0.f;
        for (int c = c0; c < c0 + 64; ++c) {
            float xv = xb[(size_t)c * 4096];
            const float4* wr = (const float4*)(Wl + c * 20);
            float4 w0 = wr[0], w1 = wr[1], w2 = wr[2], w3 = wr[3], w4 = wr[4];
            at[0] += w0.x * xv;  at[1] += w0.y * xv;  at[2] += w0.z * xv;  at[3] += w0.w * xv;
            at[4] += w1.x * xv;  at[5] += w1.y * xv;  at[6] += w1.z * xv;  at[7] += w1.w * xv;
            at[8] += w2.x * xv;  at[9] += w2.y * xv;  at[10] += w2.z * xv; at[11] += w2.w * xv;
            at[12] += w3.x * xv; at[13] += w3.y * xv; at[14] += w3.z * xv; at[15] += w3.w * xv;
            at[16] += w4.x * xv; at[17] += w4.y * xv; at[18] += w4.z * xv; at[19] += w4.w * xv;
        }
#pragma unroll
        for (int j = 0; j < 20; ++j) acc[j] += at[j];
    }

    float s[4], d[16];
#pragma unroll
    for (int j = 0; j < 4; ++j) s[j] = acc[j] + bcls[j];
#pragma unroll
    for (int j = 0; j < 16; ++j) d[j] = acc[4 + j] + bbb[j];

    float prob[4];
#pragma unroll
    for (int pr = 0; pr < 2; ++pr) {
        float m = fmaxf(s[pr], s[pr + 2]);
        float e0 = expf(s[pr] - m), e2 = expf(s[pr + 2] - m);
        float sum = e0 + e2;
        prob[pr] = e0 / sum;
        prob[pr + 2] = e2 / sum;
    }

    const float imh1 = meta[b * 3 + 0] - 1.0f;
    const float imw1 = meta[b * 3 + 1] - 1.0f;
    const float minsz = 16.0f * meta[b * 3 + 2];
    const int wp = p & 63, hp = p >> 6;
    const float cx = (float)(wp * 16 + 8), cy = (float)(hp * 16 + 8);

#pragma unroll
    for (int a = 0; a < 4; ++a) {
        float wa = (float)(64 << a);
        float pcx = d[4 * a + 0] * wa + cx;
        float pcy = d[4 * a + 1] * wa + cy;
        float pw = expf(d[4 * a + 2]) * wa;
        float ph = expf(d[4 * a + 3]) * wa;
        float x1 = pcx - 0.5f * pw, y1 = pcy - 0.5f * ph;
        float x2 = pcx + 0.5f * pw, y2 = pcy + 0.5f * ph;
        x1 = fminf(fmaxf(x1, 0.f), imw1);
        y1 = fminf(fmaxf(y1, 0.f), imh1);
        x2 = fminf(fmaxf(x2, 0.f), imw1);
        y2 = fminf(fmaxf(y2, 0.f), imh1);
        bool keep = (((x2 - x1) + 1.0f) >= minsz) && (((y2 - y1) + 1.0f) >= minsz);
        float sc = keep ? prob[a] : -__builtin_inff();
        int n = p * 4 + a;
        keys[b * 16384 + n] = ((ull)ordf(sc) << 32) | (ull)(unsigned)(16383 - n);
        float4 bx; bx.x = x1; bx.y = y1; bx.z = x2; bx.w = y2;
        boxes[b * 16384 + n] = bx;
    }
}

// ---------------- bitonic sort (descending) over uint64 keys ----------------
__global__ __launch_bounds__(512) void sort_local(ull* __restrict__ keys, int kfirst, int klast)
{
    __shared__ ull s[4096];
    const int b = blockIdx.y, chunk = blockIdx.x, tid = threadIdx.x;
    ull* g = keys + b * 16384 + chunk * 4096;
#pragma unroll
    for (int r = 0; r < 8; ++r) s[tid + 512 * r] = g[tid + 512 * r];
    __syncthreads();
    const int gbase = chunk * 4096;
    for (int k = kfirst; k <= klast; k <<= 1) {
        int j0 = (k >> 1) < 2048 ? (k >> 1) : 2048;
        for (int j = j0; j > 0; j >>= 1) {
#pragma unroll
            for (int pp = 0; pp < 4; ++pp) {
                int p = tid + 512 * pp;
                int i = ((p & ~(j - 1)) << 1) | (p & (j - 1));
                int l = i + j;
                ull a = s[i], c = s[l];
                bool up = (((gbase + i) & k) == 0);
                bool sw = up ? (a < c) : (c < a);
                if (sw) { s[i] = c; s[l] = a; }
            }
            __syncthreads();
        }
    }
#pragma unroll
    for (int r = 0; r < 8; ++r) g[tid + 512 * r] = s[tid + 512 * r];
}

__global__ __launch_bounds__(256) void sort_global_k(ull* __restrict__ keys, int k, int j)
{
    int t = blockIdx.x * 256 + threadIdx.x;
    int b = t >> 13, p = t & 8191;
    int i = ((p & ~(j - 1)) << 1) | (p & (j - 1));
    int l = i + j;
    ull* g = keys + b * 16384;
    ull a = g[i], c = g[l];
    bool up = ((i & k) == 0);
    bool sw = up ? (a < c) : (c < a);
    if (sw) { g[i] = c; g[l] = a; }
}

// ---------------- gather top-6000 sorted boxes ----------------
__global__ __launch_bounds__(256) void gather_kernel(
    const ull* __restrict__ keys, const float4* __restrict__ boxes,
    float4* __restrict__ bs, float* __restrict__ as_, ull* __restrict__ valid)
{
    const int b = blockIdx.y;
    const int i = blockIdx.x * 256 + threadIdx.x;
    bool fin = false;
    float4 box; box.x = 0.f; box.y = 0.f; box.z = 0.f; box.w = 0.f;
    float area = 1.f;
    if (i < 6000) {
        ull k = keys[b * 16384 + i];
        fin = ((unsigned)(k >> 32)) != NEGINF_ORD;
        int idx = 16383 - (int)(k & 0xFFFFFFFFull);
        box = boxes[b * 16384 + idx];
        area = ((box.z - box.x) + 1.0f) * ((box.w - box.y) + 1.0f);
    }
    bs[b * 6144 + i] = box;
    as_[b * 6144 + i] = area;
    ull m = __ballot(fin ? 1 : 0);
    if ((threadIdx.x & 63) == 0) valid[b * 96 + (i >> 6)] = m;
}

// ---------------- sequential greedy NMS with bitmask head scan ----------------
__global__ __launch_bounds__(1024) void nms_kernel(
    const float4* __restrict__ bs, const float* __restrict__ as_,
    const ull* __restrict__ valid, float* __restrict__ out)
{
    __shared__ unsigned alive[192];    // 6144 bits
    __shared__ int keepL[300];
    __shared__ int jsh;
    __shared__ int cur_sh;

    const int b = blockIdx.x, tid = threadIdx.x;

    if (tid < 96) {
        ull w = valid[b * 96 + tid];
        alive[tid * 2] = (unsigned)w;
        alive[tid * 2 + 1] = (unsigned)(w >> 32);
    }
    if (tid == 0) cur_sh = 0;
    __syncthreads();

    float4 box[6]; float area[6]; bool sf[6];
#pragma unroll
    for (int q = 0; q < 6; ++q) {
        int i = tid * 6 + q;
        box[q] = bs[b * 6144 + i];
        area[q] = as_[b * 6144 + i];
        sf[q] = !((alive[i >> 5] >> (i & 31)) & 1u);
    }
    __syncthreads();

    for (int t = 0; t < 300; ++t) {
        if (tid == 0) {
            int w = cur_sh;
            unsigned v = 0;
            while (w < 192 && (v = alive[w]) == 0u) ++w;
            int j;
            if (w < 192) {
                int bit = __ffs(v) - 1;
                j = w * 32 + bit;
                alive[w] = v & (v - 1);   // consume j
            } else {
                j = 0;
            }
            cur_sh = w;
            jsh = j; keepL[t] = j;
        }
        __syncthreads();
        const int j = jsh;
        const float4 jb = bs[b * 6144 + j];     // broadcast load, L1-cached
        const float ja = as_[b * 6144 + j];
#pragma unroll
        for (int q = 0; q < 6; ++q) {
            int i = tid * 6 + q;
            if (i == j) sf[q] = true;
            if (!sf[q] && i > j) {
                float xx1 = fmaxf(jb.x, box[q].x);
                float yy1 = fmaxf(jb.y, box[q].y);
                float xx2 = fminf(jb.z, box[q].z);
                float yy2 = fminf(jb.w, box[q].w);
                float iw = fmaxf((xx2 - xx1) + 1.0f, 0.f);
                float ih = fmaxf((yy2 - yy1) + 1.0f, 0.f);
                float inter = iw * ih;
                float iou = inter / ((ja + area[q]) - inter);
                if (iou > 0.7f) {
                    sf[q] = true;
                    atomicAnd(&alive[i >> 5], ~(1u << (i & 31)));
                }
            }
        }
        __syncthreads();
    }

    if (tid < 300) {
        int j = keepL[tid];
        float4 bx = bs[b * 6144 + j];
        float* o = out + (size_t)(b * 300 + tid) * 5;
        o[0] = (float)b; o[1] = bx.x; o[2] = bx.y; o[3] = bx.z; o[4] = bx.w;
    }
}

// ---------------- launcher ----------------
extern "C" void kernel_launch(void* const* d_in, const int* in_sizes, int n_in,
                              void* d_out, int out_size, void* d_ws, size_t ws_size,
                              hipStream_t stream) {
    const float* feat  = (const float*)d_in[0];
    const float* meta  = (const float*)d_in[1];
    const float* Wconv = (const float*)d_in[3];
    const float* bconv = (const float*)d_in[4];
    const float* Wcls  = (const float*)d_in[5];
    const float* bcls  = (const float*)d_in[6];
    const float* Wbb   = (const float*)d_in[7];
    const float* bbb   = (const float*)d_in[8];
    float* out = (float*)d_out;

    char* ws = (char*)d_ws;
    float*  x     = (float*)(ws);                       // 16,777,216 B
    float*  Wt2   = (float*)(ws + 16777216);            // 18,874,368 B
    float*  zerop = (float*)(ws + 35651584);            //      4,096 B
    ull*    keys  = (ull*)(ws + 35655680);              //    262,144 B
    float4* boxes = (float4*)(ws + 35917824);           //  1,048,576 B
    float4* bsort = (float4*)(ws + 36966400);           //    196,608 B
    float*  asort = (float*)(ws + 37163008);            //     49,152 B
    ull*    valid = (ull*)(ws + 37212160);              //      1,536 B

    zero_fill<<<1, 256, 0, stream>>>(zerop);
    reorder_w<<<dim3(16, 4, 16), 256, 0, stream>>>(Wconv, Wt2);
    conv3x3_kernel<<<dim3(16, 16, 2), 256, 0, stream>>>(Wt2, feat, zerop, bconv, x);
    head_kernel<<<dim3(16, 2), 256, 0, stream>>>(x, Wcls, bcls, Wbb, bbb, meta, keys, boxes);
    sort_local<<<dim3(4, 2), 512, 0, stream>>>(keys, 2, 4096);
    sort_global_k<<<64, 256, 0, stream>>>(keys, 8192, 4096);
    sort_local<<<dim3(4, 2), 512, 0, stream>>>(keys, 8192, 8192);
    sort_global_k<<<64, 256, 0, stream>>>(keys, 16384, 8192);
    sort_global_k<<<64, 256, 0, stream>>>(keys, 16384, 4096);
    sort_local<<<dim3(4, 2), 512, 0, stream>>>(keys, 16384, 16384);
    gather_kernel<<<dim3(24, 2), 256, 0, stream>>>(keys, boxes, bsort, asort, valid);
    nms_kernel<<<2, 1024, 0, stream>>>(bsort, asort, valid, out);
}